// Round 1
// baseline (849.095 us; speedup 1.0000x reference)
//
#include <hip/hip_runtime.h>

// GraphConv: out[t] += input[s] * (esgn*enorm), 3.2M edges, 100K nodes, D=32 fp32.
// Round 12: drop nodesort2 + seg_accum (two passes over recs + latency-bound
// serial per-node accumulate, ~140us combined). After the bucket partition,
// each bucket's output tile is 512 nodes x 32 f32 = exactly 64 KB -> fits LDS.
// New bucket_accum: per bucket, zero LDS tile, stream records fully parallel
// (32 lanes/edge, ds_add_f32 fire-and-forget -> iterations overlap), write
// tile out coalesced. Pipeline:
//   bhist(LDS) -> bscan -> partition (R6, verified, unchanged) -> bucket_accum.

#define NB   256
#define MAXK 256          // max buckets (span 512 -> n_nodes <= 131072)
#define SPAN_SHIFT 9
#define SPAN 512
#define PT   7680         // partition tile edges; srec = 60KB LDS

// Bucket-level histogram: LDS counters, one global atomic per bucket/block.
__global__ __launch_bounds__(NB) void bhist_kernel(
    const int* __restrict__ tidx, int* __restrict__ bcnt, int n_edges)
{
    __shared__ int lh[MAXK];
    for (int i = threadIdx.x; i < MAXK; i += NB) lh[i] = 0;
    __syncthreads();
    int stride = gridDim.x * NB;
    for (int e = blockIdx.x * NB + threadIdx.x; e < n_edges; e += stride)
        atomicAdd(&lh[tidx[e] >> SPAN_SHIFT], 1);
    __syncthreads();
    for (int i = threadIdx.x; i < MAXK; i += NB)
        if (lh[i]) atomicAdd(&bcnt[i], lh[i]);
}

// Exclusive scan over MAXK bucket counts -> bbase[0..MAXK], bcur=bbase.
__global__ __launch_bounds__(MAXK) void bscan_kernel(
    const int* __restrict__ bcnt, int* __restrict__ bbase, int* __restrict__ bcur)
{
    __shared__ int part[MAXK];
    int t = threadIdx.x;
    int c = bcnt[t];
    part[t] = c;
    __syncthreads();
    for (int off = 1; off < MAXK; off <<= 1) {
        int v = (t >= off) ? part[t - off] : 0;
        __syncthreads();
        part[t] += v;
        __syncthreads();
    }
    int excl = part[t] - c;
    bbase[t] = excl;
    bcur[t] = excl;
    if (t == MAXK - 1) bbase[MAXK] = part[MAXK - 1];
}

// R6 partition (verified): tile-local bucket sort in LDS, contiguous run writes.
__global__ __launch_bounds__(NB) void partition_kernel(
    const int* __restrict__ sidx, const int* __restrict__ tidx,
    const float* __restrict__ enorm, const float* __restrict__ esgn,
    int* __restrict__ bcur, int2* __restrict__ recs, int n_edges)
{
    __shared__ int2 srec[PT];              // 60 KB
    __shared__ int lh[MAXK];
    __shared__ int lbase[MAXK];
    __shared__ int lcur[MAXK];
    __shared__ int gb[MAXK];
    int t = threadIdx.x;
    lh[t] = 0;
    __syncthreads();

    size_t tb = (size_t)blockIdx.x * PT;
    for (int j = 0; j < PT / NB; ++j) {
        int e = (int)tb + j * NB + t;
        if (e < n_edges) atomicAdd(&lh[tidx[e] >> SPAN_SHIFT], 1);
    }
    __syncthreads();
    int c = lh[t];
    lbase[t] = c;
    __syncthreads();
    for (int off = 1; off < MAXK; off <<= 1) {
        int v = (t >= off) ? lbase[t - off] : 0;
        __syncthreads();
        lbase[t] += v;
        __syncthreads();
    }
    int excl = lbase[t] - c;
    __syncthreads();
    lbase[t] = excl;
    lcur[t] = excl;
    if (c > 0) gb[t] = atomicAdd(&bcur[t], c);
    __syncthreads();
    for (int j = 0; j < PT / NB; ++j) {
        int e = (int)tb + j * NB + t;
        if (e < n_edges) {
            int tn = tidx[e];
            int b = tn >> SPAN_SHIFT;
            unsigned rec = ((unsigned)sidx[e] << SPAN_SHIFT) | (unsigned)(tn & (SPAN - 1));
            float w = enorm[e] * esgn[e];
            int p = atomicAdd(&lcur[b], 1);
            srec[p] = make_int2((int)rec, __float_as_int(w));
        }
    }
    __syncthreads();
    int cnt = lh[t];
    if (cnt > 0) {
        int lb = lbase[t];
        int g = gb[t];
        for (int i = 0; i < cnt; ++i) recs[g + i] = srec[lb + i];
    }
}

// Per-bucket accumulate directly in LDS: tile = 512 nodes x 32 f32 = 64 KB.
// 32 lanes per edge (lane = feature); ds_add_f32 is fire-and-forget, so
// iterations overlap (no dependent gather->fma chain like the old seg_accum).
// Bank pattern: two edges per wave64 at the same column = 2-way conflict = free.
__global__ __launch_bounds__(1024) void bucket_accum(
    const float* __restrict__ input, const int2* __restrict__ recs,
    const int* __restrict__ bbase, float* __restrict__ out, int n_nodes)
{
    __shared__ float tile[SPAN * 32];      // 64 KB exactly
    int t = threadIdx.x;
    int b = blockIdx.x;
    for (int i = t; i < SPAN * 32; i += 1024) tile[i] = 0.f;
    __syncthreads();

    int bstart = bbase[b], bend = bbase[b + 1];
    int grp  = t >> 5;                     // 32 edge-groups per block
    int lane = t & 31;                     // feature index

    int i = bstart + grp;
    // 4-deep manual unroll: 4 outstanding gathers per group for MLP.
    for (; i + 96 < bend; i += 128) {
        int2 r0 = recs[i];
        int2 r1 = recs[i + 32];
        int2 r2 = recs[i + 64];
        int2 r3 = recs[i + 96];
        float v0 = input[(size_t)(((unsigned)r0.x) >> SPAN_SHIFT) * 32 + lane];
        float v1 = input[(size_t)(((unsigned)r1.x) >> SPAN_SHIFT) * 32 + lane];
        float v2 = input[(size_t)(((unsigned)r2.x) >> SPAN_SHIFT) * 32 + lane];
        float v3 = input[(size_t)(((unsigned)r3.x) >> SPAN_SHIFT) * 32 + lane];
        atomicAdd(&tile[((r0.x & (SPAN - 1)) << 5) + lane], __int_as_float(r0.y) * v0);
        atomicAdd(&tile[((r1.x & (SPAN - 1)) << 5) + lane], __int_as_float(r1.y) * v1);
        atomicAdd(&tile[((r2.x & (SPAN - 1)) << 5) + lane], __int_as_float(r2.y) * v2);
        atomicAdd(&tile[((r3.x & (SPAN - 1)) << 5) + lane], __int_as_float(r3.y) * v3);
    }
    for (; i < bend; i += 32) {
        int2 r = recs[i];
        float v = input[(size_t)(((unsigned)r.x) >> SPAN_SHIFT) * 32 + lane];
        atomicAdd(&tile[((r.x & (SPAN - 1)) << 5) + lane], __int_as_float(r.y) * v);
    }
    __syncthreads();

    // Coalesced tile flush: out linear index = base_node*32 + i.
    size_t obase = (size_t)b << (SPAN_SHIFT + 5);
    size_t olim  = (size_t)n_nodes * 32;
    for (int j = t; j < SPAN * 32; j += 1024) {
        size_t o = obase + (size_t)j;
        if (o < olim) out[o] = tile[j];
    }
}

// Last-resort fallback (R3): direct atomic scatter.
__global__ __launch_bounds__(NB) void graphconv_scatter(
    const float* __restrict__ input, const int* __restrict__ sidx,
    const int* __restrict__ tidx, const float* __restrict__ enorm,
    const float* __restrict__ esgn, float* __restrict__ out, int n_edges)
{
    int t = blockIdx.x * NB + threadIdx.x;
    int e = t >> 3;
    int sub = t & 7;
    if (e >= n_edges) return;
    int s = sidx[e];
    int d = tidx[e];
    float w = enorm[e] * esgn[e];
    const float4* src = (const float4*)(input + (size_t)s * 32);
    float4 v = src[sub];
    float* op = out + (size_t)d * 32 + sub * 4;
    atomicAdd(op + 0, v.x * w);
    atomicAdd(op + 1, v.y * w);
    atomicAdd(op + 2, v.z * w);
    atomicAdd(op + 3, v.w * w);
}

extern "C" void kernel_launch(void* const* d_in, const int* in_sizes, int n_in,
                              void* d_out, int out_size, void* d_ws, size_t ws_size,
                              hipStream_t stream) {
    const float* input = (const float*)d_in[0];
    const int*   eidx  = (const int*)d_in[1];   // int64 in reference -> int32 here
    const float* enorm = (const float*)d_in[2];
    const float* esgn  = (const float*)d_in[3];
    float*       out   = (float*)d_out;

    int n_edges = in_sizes[1] / 2;             // eidx is (2, n_edges)
    int n_nodes = in_sizes[0] / 32;            // input is (n_nodes, 32)
    const int* sidx = eidx;
    const int* tidx = eidx + n_edges;

    int K = (n_nodes + SPAN - 1) >> SPAN_SHIFT;   // 196

    // Workspace: recs[E int2] | bcnt[MAXK] | bbase[MAXK+1] | bcur[MAXK]
    size_t need = (size_t)n_edges * 8 + (3 * MAXK + 1) * 4;

    if (ws_size >= need && K <= MAXK) {
        int2* recs    = (int2*)d_ws;
        int*  bcnt    = (int*)(recs + n_edges);
        int*  bbase   = bcnt + MAXK;
        int*  bcur    = bbase + (MAXK + 1);

        hipMemsetAsync(bcnt, 0, MAXK * sizeof(int), stream);

        bhist_kernel    <<<1024, NB,   0, stream>>>(tidx, bcnt, n_edges);
        bscan_kernel    <<<1,    MAXK, 0, stream>>>(bcnt, bbase, bcur);
        int pg = (n_edges + PT - 1) / PT;
        partition_kernel<<<pg,   NB,   0, stream>>>(sidx, tidx, enorm, esgn,
                                                    bcur, recs, n_edges);
        bucket_accum    <<<K,    1024, 0, stream>>>(input, recs, bbase,
                                                    out, n_nodes);
    } else {
        hipMemsetAsync(d_out, 0, (size_t)out_size * sizeof(float), stream);
        size_t threads_total = (size_t)n_edges * 8;
        int grid = (int)((threads_total + NB - 1) / NB);
        graphconv_scatter<<<grid, NB, 0, stream>>>(input, sidx, tidx, enorm, esgn,
                                                   out, n_edges);
    }
}

// Round 3
// 266.579 us; speedup vs baseline: 3.1852x; 3.1852x over previous
//
#include <hip/hip_runtime.h>

// GraphConv: out[t] += input[s] * (esgn*enorm), 3.2M edges, 100K nodes, D=32 fp32.
// Round 14: R13 failed to bench (container died; sole risky change was
// partition LDS growing 64->71.5KB via sbucket[PT]). Same two optimizations,
// de-risked:
//   (a) partition copy-out element-parallel WITHOUT sbucket: recover bucket id
//       per element via 8-step binary search over lbase[256] in LDS (last b
//       with lbase[b] <= p; ties skip empty buckets correctly). LDS stays at
//       the verified 64KB.
//   (b) seg_accum 4-deep unroll: 8 outstanding float4 gathers per lane.
// Pipeline: bhist -> bscan -> partition -> nodesort2 -> seg_accum (verified).

#define NB   256
#define MAXK 256          // max buckets (span 512 -> n_nodes <= 131072)
#define SPAN_SHIFT 9
#define SPAN 512
#define PT   7680         // partition tile edges; srec = 60KB LDS

// Bucket-level histogram: LDS counters, one global atomic per bucket/block.
__global__ __launch_bounds__(NB) void bhist_kernel(
    const int* __restrict__ tidx, int* __restrict__ bcnt, int n_edges)
{
    __shared__ int lh[MAXK];
    for (int i = threadIdx.x; i < MAXK; i += NB) lh[i] = 0;
    __syncthreads();
    int stride = gridDim.x * NB;
    for (int e = blockIdx.x * NB + threadIdx.x; e < n_edges; e += stride)
        atomicAdd(&lh[tidx[e] >> SPAN_SHIFT], 1);
    __syncthreads();
    for (int i = threadIdx.x; i < MAXK; i += NB)
        if (lh[i]) atomicAdd(&bcnt[i], lh[i]);
}

// Exclusive scan over MAXK bucket counts -> bbase[0..MAXK], bcur=bbase.
__global__ __launch_bounds__(MAXK) void bscan_kernel(
    const int* __restrict__ bcnt, int* __restrict__ bbase, int* __restrict__ bcur)
{
    __shared__ int part[MAXK];
    int t = threadIdx.x;
    int c = bcnt[t];
    part[t] = c;
    __syncthreads();
    for (int off = 1; off < MAXK; off <<= 1) {
        int v = (t >= off) ? part[t - off] : 0;
        __syncthreads();
        part[t] += v;
        __syncthreads();
    }
    int excl = part[t] - c;
    bbase[t] = excl;
    bcur[t] = excl;
    if (t == MAXK - 1) bbase[MAXK] = part[MAXK - 1];
}

// Partition: tile-local bucket sort in LDS. R14: element-parallel copy-out,
// bucket id recovered by binary search over lbase (LDS stays 64KB).
__global__ __launch_bounds__(NB) void partition_kernel(
    const int* __restrict__ sidx, const int* __restrict__ tidx,
    const float* __restrict__ enorm, const float* __restrict__ esgn,
    int* __restrict__ bcur, int2* __restrict__ recs, int n_edges)
{
    __shared__ int2 srec[PT];              // 60 KB
    __shared__ int lh[MAXK];
    __shared__ int lbase[MAXK];
    __shared__ int lcur[MAXK];
    __shared__ int gb[MAXK];
    int t = threadIdx.x;
    lh[t] = 0;
    __syncthreads();

    size_t tb = (size_t)blockIdx.x * PT;
    int nvalid = n_edges - (int)tb;
    if (nvalid > PT) nvalid = PT;

    for (int j = 0; j < PT / NB; ++j) {
        int e = (int)tb + j * NB + t;
        if (e < n_edges) atomicAdd(&lh[tidx[e] >> SPAN_SHIFT], 1);
    }
    __syncthreads();
    int c = lh[t];
    lbase[t] = c;
    __syncthreads();
    for (int off = 1; off < MAXK; off <<= 1) {
        int v = (t >= off) ? lbase[t - off] : 0;
        __syncthreads();
        lbase[t] += v;
        __syncthreads();
    }
    int excl = lbase[t] - c;
    __syncthreads();
    lbase[t] = excl;
    lcur[t] = excl;
    if (c > 0) gb[t] = atomicAdd(&bcur[t], c);
    __syncthreads();
    for (int j = 0; j < PT / NB; ++j) {
        int e = (int)tb + j * NB + t;
        if (e < n_edges) {
            int tn = tidx[e];
            int b = tn >> SPAN_SHIFT;
            unsigned rec = ((unsigned)sidx[e] << SPAN_SHIFT) | (unsigned)(tn & (SPAN - 1));
            float w = enorm[e] * esgn[e];
            int p = atomicAdd(&lcur[b], 1);
            srec[p] = make_int2((int)rec, __float_as_int(w));
        }
    }
    __syncthreads();
    // Element-parallel copy-out: bucket of element p = last b with lbase[b]<=p
    // (8-step binary search in LDS). Coalesced within runs, no serial chains.
    for (int p = t; p < nvalid; p += NB) {
        int lo = 0, hi = MAXK - 1;
        #pragma unroll
        for (int s = 0; s < 8; ++s) {
            int mid = (lo + hi + 1) >> 1;
            if (lbase[mid] <= p) lo = mid; else hi = mid - 1;
        }
        recs[gb[lo] + (p - lbase[lo])] = srec[p];
    }
}

// Fused per-bucket node hist + scan + scatter. Bucket recs are L2-hot
// (~130KB); two passes. Writes nodeoff and the node-sorted rec array.
__global__ __launch_bounds__(1024) void nodesort2_kernel(
    const int2* __restrict__ recs, const int* __restrict__ bbase,
    int* __restrict__ nodeoff, int2* __restrict__ sorted, int n_nodes, int K)
{
    __shared__ int lcnt[SPAN];
    __shared__ int lpart[SPAN];
    __shared__ int lcur[SPAN];
    int b = blockIdx.x;
    int t = threadIdx.x;
    int base_node = b << SPAN_SHIFT;
    int bstart = bbase[b], bend = bbase[b + 1];

    for (int i = t; i < SPAN; i += 1024) lcnt[i] = 0;
    __syncthreads();
    // pass A: node histogram for this bucket
    for (int i = bstart + t; i < bend; i += 1024)
        atomicAdd(&lcnt[recs[i].x & (SPAN - 1)], 1);
    __syncthreads();
    // LDS exclusive scan over SPAN=512 (threads 0-511 active; barriers uniform)
    int c = (t < SPAN) ? lcnt[t] : 0;
    if (t < SPAN) lpart[t] = c;
    __syncthreads();
    for (int off = 1; off < SPAN; off <<= 1) {
        int v = (t < SPAN && t >= off) ? lpart[t - off] : 0;
        __syncthreads();
        if (t < SPAN) lpart[t] += v;
        __syncthreads();
    }
    if (t < SPAN) {
        int excl = lpart[t] - c;
        int node = base_node + t;
        int gpos = bstart + excl;
        lcur[t] = gpos;
        if (node < n_nodes) nodeoff[node] = gpos;
    }
    if (b == K - 1 && t == 0) nodeoff[n_nodes] = bend;
    __syncthreads();
    // pass B: scatter to node-sorted order
    for (int i = bstart + t; i < bend; i += 1024) {
        int2 r = recs[i];
        int pos = atomicAdd(&lcur[r.x & (SPAN - 1)], 1);
        sorted[pos] = r;
    }
}

// Segmented accumulate: 8 lanes per node, float4 per lane; no atomics.
// R14: 4-deep unroll -> 8 outstanding loads per lane (was 1, latency-bound).
__global__ __launch_bounds__(NB) void seg_accum(
    const float* __restrict__ input, const int2* __restrict__ sorted,
    const int* __restrict__ nodeoff, float* __restrict__ out, int n_nodes)
{
    int n = blockIdx.x * 32 + (threadIdx.x >> 3);
    int lane = threadIdx.x & 7;
    if (n >= n_nodes) return;
    int beg = nodeoff[n], end = nodeoff[n + 1];
    float4 acc = make_float4(0.f, 0.f, 0.f, 0.f);
    int i = beg;
    for (; i + 3 < end; i += 4) {
        int2 r0 = sorted[i];
        int2 r1 = sorted[i + 1];
        int2 r2 = sorted[i + 2];
        int2 r3 = sorted[i + 3];
        float4 v0 = ((const float4*)(input + (size_t)(((unsigned)r0.x) >> SPAN_SHIFT) * 32))[lane];
        float4 v1 = ((const float4*)(input + (size_t)(((unsigned)r1.x) >> SPAN_SHIFT) * 32))[lane];
        float4 v2 = ((const float4*)(input + (size_t)(((unsigned)r2.x) >> SPAN_SHIFT) * 32))[lane];
        float4 v3 = ((const float4*)(input + (size_t)(((unsigned)r3.x) >> SPAN_SHIFT) * 32))[lane];
        float w0 = __int_as_float(r0.y);
        float w1 = __int_as_float(r1.y);
        float w2 = __int_as_float(r2.y);
        float w3 = __int_as_float(r3.y);
        acc.x = fmaf(w0, v0.x, acc.x);
        acc.y = fmaf(w0, v0.y, acc.y);
        acc.z = fmaf(w0, v0.z, acc.z);
        acc.w = fmaf(w0, v0.w, acc.w);
        acc.x = fmaf(w1, v1.x, acc.x);
        acc.y = fmaf(w1, v1.y, acc.y);
        acc.z = fmaf(w1, v1.z, acc.z);
        acc.w = fmaf(w1, v1.w, acc.w);
        acc.x = fmaf(w2, v2.x, acc.x);
        acc.y = fmaf(w2, v2.y, acc.y);
        acc.z = fmaf(w2, v2.z, acc.z);
        acc.w = fmaf(w2, v2.w, acc.w);
        acc.x = fmaf(w3, v3.x, acc.x);
        acc.y = fmaf(w3, v3.y, acc.y);
        acc.z = fmaf(w3, v3.z, acc.z);
        acc.w = fmaf(w3, v3.w, acc.w);
    }
    for (; i < end; ++i) {
        int2 r = sorted[i];
        float w = __int_as_float(r.y);
        float4 v = ((const float4*)(input + (size_t)(((unsigned)r.x) >> SPAN_SHIFT) * 32))[lane];
        acc.x = fmaf(w, v.x, acc.x);
        acc.y = fmaf(w, v.y, acc.y);
        acc.z = fmaf(w, v.z, acc.z);
        acc.w = fmaf(w, v.w, acc.w);
    }
    ((float4*)(out + (size_t)n * 32))[lane] = acc;
}

// Last-resort fallback (R3): direct atomic scatter.
__global__ __launch_bounds__(NB) void graphconv_scatter(
    const float* __restrict__ input, const int* __restrict__ sidx,
    const int* __restrict__ tidx, const float* __restrict__ enorm,
    const float* __restrict__ esgn, float* __restrict__ out, int n_edges)
{
    int t = blockIdx.x * NB + threadIdx.x;
    int e = t >> 3;
    int sub = t & 7;
    if (e >= n_edges) return;
    int s = sidx[e];
    int d = tidx[e];
    float w = enorm[e] * esgn[e];
    const float4* src = (const float4*)(input + (size_t)s * 32);
    float4 v = src[sub];
    float* op = out + (size_t)d * 32 + sub * 4;
    atomicAdd(op + 0, v.x * w);
    atomicAdd(op + 1, v.y * w);
    atomicAdd(op + 2, v.z * w);
    atomicAdd(op + 3, v.w * w);
}

extern "C" void kernel_launch(void* const* d_in, const int* in_sizes, int n_in,
                              void* d_out, int out_size, void* d_ws, size_t ws_size,
                              hipStream_t stream) {
    const float* input = (const float*)d_in[0];
    const int*   eidx  = (const int*)d_in[1];   // int64 in reference -> int32 here
    const float* enorm = (const float*)d_in[2];
    const float* esgn  = (const float*)d_in[3];
    float*       out   = (float*)d_out;

    int n_edges = in_sizes[1] / 2;             // eidx is (2, n_edges)
    int n_nodes = in_sizes[0] / 32;            // input is (n_nodes, 32)
    const int* sidx = eidx;
    const int* tidx = eidx + n_edges;

    int K = (n_nodes + SPAN - 1) >> SPAN_SHIFT;   // 196

    // Workspace: sorted[E int2] | recs[E int2] | nodeoff[n+1]
    //            | bcnt[MAXK] | bbase[MAXK+1] | bcur[MAXK]
    size_t need = (size_t)n_edges * 16 +
                  ((size_t)n_nodes + 1 + 3 * MAXK + 1) * 4;

    if (ws_size >= need && K <= MAXK) {
        int2* sorted  = (int2*)d_ws;
        int2* recs    = sorted + n_edges;
        int*  nodeoff = (int*)(recs + n_edges);
        int*  bcnt    = nodeoff + (n_nodes + 1);
        int*  bbase   = bcnt + MAXK;
        int*  bcur    = bbase + (MAXK + 1);

        hipMemsetAsync(bcnt, 0, MAXK * sizeof(int), stream);

        bhist_kernel    <<<1024, NB,   0, stream>>>(tidx, bcnt, n_edges);
        bscan_kernel    <<<1,    MAXK, 0, stream>>>(bcnt, bbase, bcur);
        int pg = (n_edges + PT - 1) / PT;
        partition_kernel<<<pg,   NB,   0, stream>>>(sidx, tidx, enorm, esgn,
                                                    bcur, recs, n_edges);
        nodesort2_kernel<<<K,    1024, 0, stream>>>(recs, bbase, nodeoff,
                                                    sorted, n_nodes, K);
        int ag = (n_nodes + 31) / 32;
        seg_accum       <<<ag,   NB,   0, stream>>>(input, sorted, nodeoff,
                                                    out, n_nodes);
    } else {
        hipMemsetAsync(d_out, 0, (size_t)out_size * sizeof(float), stream);
        size_t threads_total = (size_t)n_edges * 8;
        int grid = (int)((threads_total + NB - 1) / NB);
        graphconv_scatter<<<grid, NB, 0, stream>>>(input, sidx, tidx, enorm, esgn,
                                                   out, n_edges);
    }
}

// Round 4
// 258.103 us; speedup vs baseline: 3.2897x; 1.0328x over previous
//
#include <hip/hip_runtime.h>

// GraphConv: out[t] += input[s] * (esgn*enorm), 3.2M edges, 100K nodes, D=32 fp32.
// Round 15: shrink bucket span 512->128 so one bucket's records fit in LDS
// (avg 4096 recs = 32KB, cap 6144 = 48KB). nodesort2+seg_accum fuse into
// bucket_accum: hist -> scan -> scatter into LDS -> 8-lane/node float4
// accumulate (R14's proven 4-deep unroll, now fed from LDS). Deletes the
// 'sorted' global round-trip (51MB), nodeoff, and one kernel boundary.
// Parallelism preserved: 782 blocks x 1024 thr = 800K chains (= seg_accum).
// Adversarial bucket overflow (>CAP recs) -> correct atomic fallback path.
// Pipeline: bhist -> bscan -> partition -> bucket_accum.

#define NB   256
#define KMAX 1024         // max buckets (span 128 -> n_nodes <= 131072)
#define SPAN_SHIFT 7
#define SPAN 128
#define PT   5888         // partition tile edges (=256*23); srec = 46KB LDS
#define PTC  (PT / NB)    // 23
#define CAP  6144         // bucket_accum LDS record capacity (48KB)

// Bucket-level histogram: LDS counters, one global atomic per bucket/block.
__global__ __launch_bounds__(NB) void bhist_kernel(
    const int* __restrict__ tidx, int* __restrict__ bcnt, int n_edges)
{
    __shared__ int lh[KMAX];
    for (int i = threadIdx.x; i < KMAX; i += NB) lh[i] = 0;
    __syncthreads();
    int stride = gridDim.x * NB;
    for (int e = blockIdx.x * NB + threadIdx.x; e < n_edges; e += stride)
        atomicAdd(&lh[tidx[e] >> SPAN_SHIFT], 1);
    __syncthreads();
    for (int i = threadIdx.x; i < KMAX; i += NB)
        if (lh[i]) atomicAdd(&bcnt[i], lh[i]);
}

// Exclusive scan over K (<=1024) bucket counts -> bbase[0..K].
__global__ __launch_bounds__(1024) void bscan_kernel(
    const int* __restrict__ bcnt, int* __restrict__ bbase, int K)
{
    __shared__ int part[KMAX];
    int t = threadIdx.x;
    int c = (t < K) ? bcnt[t] : 0;
    part[t] = c;
    __syncthreads();
    for (int off = 1; off < KMAX; off <<= 1) {
        int v = (t >= off) ? part[t - off] : 0;
        __syncthreads();
        part[t] += v;
        __syncthreads();
    }
    if (t < K) bbase[t] = part[t] - c;
    if (t == K - 1) bbase[K] = part[t];
}

// Partition into K<=1024 buckets: tile-local LDS bucket sort, chunked scan
// (4 buckets/thread), global base via bbase + zero-init bcur0 reservation,
// serial-run coalesced copy-out (R0-style, runs now avg ~8 recs).
__global__ __launch_bounds__(NB) void partition_kernel(
    const int* __restrict__ sidx, const int* __restrict__ tidx,
    const float* __restrict__ enorm, const float* __restrict__ esgn,
    const int* __restrict__ bbase, int* __restrict__ bcur0,
    int2* __restrict__ recs, int n_edges)
{
    __shared__ int2 srec[PT];              // 46 KB
    __shared__ int lh[KMAX];               // 4 KB
    __shared__ int lbase[KMAX];            // 4 KB
    __shared__ int lcur[KMAX];             // 4 KB
    __shared__ int gb[KMAX];               // 4 KB
    __shared__ int ctot[NB];               // 1 KB   (total 63 KB)
    int t = threadIdx.x;
    for (int i = t; i < KMAX; i += NB) lh[i] = 0;
    __syncthreads();

    size_t tb = (size_t)blockIdx.x * PT;
    for (int j = 0; j < PTC; ++j) {
        int e = (int)tb + j * NB + t;
        if (e < n_edges) atomicAdd(&lh[tidx[e] >> SPAN_SHIFT], 1);
    }
    __syncthreads();
    // chunked exclusive scan over KMAX buckets: thread t owns [4t, 4t+4)
    int b0 = t << 2;
    int v0 = lh[b0], v1 = lh[b0 + 1], v2 = lh[b0 + 2], v3 = lh[b0 + 3];
    int sum = v0 + v1 + v2 + v3;
    ctot[t] = sum;
    __syncthreads();
    for (int off = 1; off < NB; off <<= 1) {
        int v = (t >= off) ? ctot[t - off] : 0;
        __syncthreads();
        ctot[t] += v;
        __syncthreads();
    }
    int run = ctot[t] - sum;               // exclusive prefix of this chunk
    lbase[b0] = run;     lcur[b0] = run;     run += v0;
    lbase[b0 + 1] = run; lcur[b0 + 1] = run; run += v1;
    lbase[b0 + 2] = run; lcur[b0 + 2] = run; run += v2;
    lbase[b0 + 3] = run; lcur[b0 + 3] = run;
    // global reservation per bucket (order-insensitive)
    if (v0 > 0) gb[b0]     = bbase[b0]     + atomicAdd(&bcur0[b0],     v0);
    if (v1 > 0) gb[b0 + 1] = bbase[b0 + 1] + atomicAdd(&bcur0[b0 + 1], v1);
    if (v2 > 0) gb[b0 + 2] = bbase[b0 + 2] + atomicAdd(&bcur0[b0 + 2], v2);
    if (v3 > 0) gb[b0 + 3] = bbase[b0 + 3] + atomicAdd(&bcur0[b0 + 3], v3);
    __syncthreads();
    // scatter into LDS in bucket order
    for (int j = 0; j < PTC; ++j) {
        int e = (int)tb + j * NB + t;
        if (e < n_edges) {
            int tn = tidx[e];
            int b = tn >> SPAN_SHIFT;
            unsigned rec = ((unsigned)sidx[e] << SPAN_SHIFT) | (unsigned)(tn & (SPAN - 1));
            float w = enorm[e] * esgn[e];
            int p = atomicAdd(&lcur[b], 1);
            srec[p] = make_int2((int)rec, __float_as_int(w));
        }
    }
    __syncthreads();
    // copy-out: 4 buckets per thread, contiguous runs (avg ~8 recs each)
    for (int q = 0; q < 4; ++q) {
        int b = b0 + q;
        int cnt = lh[b];
        if (cnt > 0) {
            int lb = lbase[b];
            int g = gb[b];
            for (int i = 0; i < cnt; ++i) recs[g + i] = srec[lb + i];
        }
    }
}

// Fused node-sort + accumulate, one block per bucket (128 nodes).
// Normal path: bucket records staged & node-sorted entirely in LDS, then
// 8 lanes/node x float4 accumulate with 4-deep unroll (no atomics, no
// 'sorted' global array). Overflow path (cnt > CAP, adversarial only):
// zero rows, atomic accumulate from global recs (disjoint rows per block).
__global__ __launch_bounds__(1024) void bucket_accum(
    const float* __restrict__ input, const int2* __restrict__ recs,
    const int* __restrict__ bbase, float* __restrict__ out, int n_nodes)
{
    __shared__ int2 srec[CAP];             // 48 KB
    __shared__ int lcnt[SPAN];
    __shared__ int lbeg[SPAN];
    __shared__ int lcur[SPAN];
    int b = blockIdx.x;
    int t = threadIdx.x;
    int bstart = bbase[b], bend = bbase[b + 1];
    int base_node = b << SPAN_SHIFT;

    if (bend - bstart <= CAP) {
        if (t < SPAN) lcnt[t] = 0;
        __syncthreads();
        // node histogram
        for (int i = bstart + t; i < bend; i += 1024)
            atomicAdd(&lcnt[recs[i].x & (SPAN - 1)], 1);
        __syncthreads();
        // exclusive scan over SPAN=128 (masked H-S, uniform barriers)
        int c = (t < SPAN) ? lcnt[t] : 0;
        if (t < SPAN) lbeg[t] = c;
        __syncthreads();
        for (int off = 1; off < SPAN; off <<= 1) {
            int v = (t < SPAN && t >= off) ? lbeg[t - off] : 0;
            __syncthreads();
            if (t < SPAN) lbeg[t] += v;
            __syncthreads();
        }
        if (t < SPAN) {
            int excl = lbeg[t] - c;
            lbeg[t] = excl;
            lcur[t] = excl;
        }
        __syncthreads();
        // scatter into LDS, node-sorted
        for (int i = bstart + t; i < bend; i += 1024) {
            int2 r = recs[i];
            int pos = atomicAdd(&lcur[r.x & (SPAN - 1)], 1);
            srec[pos] = r;
        }
        __syncthreads();
        // accumulate: 8 lanes per node, float4 per lane, 4-deep unroll
        int node = t >> 3;
        int lane = t & 7;
        int beg = lbeg[node];
        int end = beg + lcnt[node];
        float4 acc = make_float4(0.f, 0.f, 0.f, 0.f);
        int i = beg;
        for (; i + 3 < end; i += 4) {
            int2 r0 = srec[i];
            int2 r1 = srec[i + 1];
            int2 r2 = srec[i + 2];
            int2 r3 = srec[i + 3];
            float4 v0 = ((const float4*)(input + (size_t)(((unsigned)r0.x) >> SPAN_SHIFT) * 32))[lane];
            float4 v1 = ((const float4*)(input + (size_t)(((unsigned)r1.x) >> SPAN_SHIFT) * 32))[lane];
            float4 v2 = ((const float4*)(input + (size_t)(((unsigned)r2.x) >> SPAN_SHIFT) * 32))[lane];
            float4 v3 = ((const float4*)(input + (size_t)(((unsigned)r3.x) >> SPAN_SHIFT) * 32))[lane];
            float w0 = __int_as_float(r0.y);
            float w1 = __int_as_float(r1.y);
            float w2 = __int_as_float(r2.y);
            float w3 = __int_as_float(r3.y);
            acc.x = fmaf(w0, v0.x, acc.x);
            acc.y = fmaf(w0, v0.y, acc.y);
            acc.z = fmaf(w0, v0.z, acc.z);
            acc.w = fmaf(w0, v0.w, acc.w);
            acc.x = fmaf(w1, v1.x, acc.x);
            acc.y = fmaf(w1, v1.y, acc.y);
            acc.z = fmaf(w1, v1.z, acc.z);
            acc.w = fmaf(w1, v1.w, acc.w);
            acc.x = fmaf(w2, v2.x, acc.x);
            acc.y = fmaf(w2, v2.y, acc.y);
            acc.z = fmaf(w2, v2.z, acc.z);
            acc.w = fmaf(w2, v2.w, acc.w);
            acc.x = fmaf(w3, v3.x, acc.x);
            acc.y = fmaf(w3, v3.y, acc.y);
            acc.z = fmaf(w3, v3.z, acc.z);
            acc.w = fmaf(w3, v3.w, acc.w);
        }
        for (; i < end; ++i) {
            int2 r = srec[i];
            float w = __int_as_float(r.y);
            float4 v = ((const float4*)(input + (size_t)(((unsigned)r.x) >> SPAN_SHIFT) * 32))[lane];
            acc.x = fmaf(w, v.x, acc.x);
            acc.y = fmaf(w, v.y, acc.y);
            acc.z = fmaf(w, v.z, acc.z);
            acc.w = fmaf(w, v.w, acc.w);
        }
        int gnode = base_node + node;
        if (gnode < n_nodes)
            ((float4*)(out + (size_t)gnode * 32))[lane] = acc;
    } else {
        // overflow fallback (correctness only; ~never taken on random data)
        for (int i = t; i < SPAN * 32; i += 1024) {
            int gn = base_node + (i >> 5);
            if (gn < n_nodes) out[(size_t)gn * 32 + (i & 31)] = 0.f;
        }
        __syncthreads();
        for (int i = bstart + t; i < bend; i += 1024) {
            int2 r = recs[i];
            float w = __int_as_float(r.y);
            int s = (int)(((unsigned)r.x) >> SPAN_SHIFT);
            int gn = base_node + (r.x & (SPAN - 1));
            if (gn < n_nodes)
                for (int j = 0; j < 32; ++j)
                    atomicAdd(&out[(size_t)gn * 32 + j], w * input[(size_t)s * 32 + j]);
        }
    }
}

// Last-resort fallback (R3): direct atomic scatter.
__global__ __launch_bounds__(NB) void graphconv_scatter(
    const float* __restrict__ input, const int* __restrict__ sidx,
    const int* __restrict__ tidx, const float* __restrict__ enorm,
    const float* __restrict__ esgn, float* __restrict__ out, int n_edges)
{
    int t = blockIdx.x * NB + threadIdx.x;
    int e = t >> 3;
    int sub = t & 7;
    if (e >= n_edges) return;
    int s = sidx[e];
    int d = tidx[e];
    float w = enorm[e] * esgn[e];
    const float4* src = (const float4*)(input + (size_t)s * 32);
    float4 v = src[sub];
    float* op = out + (size_t)d * 32 + sub * 4;
    atomicAdd(op + 0, v.x * w);
    atomicAdd(op + 1, v.y * w);
    atomicAdd(op + 2, v.z * w);
    atomicAdd(op + 3, v.w * w);
}

extern "C" void kernel_launch(void* const* d_in, const int* in_sizes, int n_in,
                              void* d_out, int out_size, void* d_ws, size_t ws_size,
                              hipStream_t stream) {
    const float* input = (const float*)d_in[0];
    const int*   eidx  = (const int*)d_in[1];   // int64 in reference -> int32 here
    const float* enorm = (const float*)d_in[2];
    const float* esgn  = (const float*)d_in[3];
    float*       out   = (float*)d_out;

    int n_edges = in_sizes[1] / 2;             // eidx is (2, n_edges)
    int n_nodes = in_sizes[0] / 32;            // input is (n_nodes, 32)
    const int* sidx = eidx;
    const int* tidx = eidx + n_edges;

    int K = (n_nodes + SPAN - 1) >> SPAN_SHIFT;   // 782 for 100K nodes

    // Workspace: recs[E int2] | bcnt[KMAX] | bcur0[KMAX] | bbase[KMAX+1]
    size_t need = (size_t)n_edges * 8 + (3 * KMAX + 1) * 4;

    if (ws_size >= need && K <= KMAX) {
        int2* recs  = (int2*)d_ws;
        int*  bcnt  = (int*)(recs + n_edges);
        int*  bcur0 = bcnt + KMAX;
        int*  bbase = bcur0 + KMAX;

        hipMemsetAsync(bcnt, 0, 2 * KMAX * sizeof(int), stream);  // bcnt + bcur0

        bhist_kernel    <<<1024, NB,   0, stream>>>(tidx, bcnt, n_edges);
        bscan_kernel    <<<1,    KMAX, 0, stream>>>(bcnt, bbase, K);
        int pg = (n_edges + PT - 1) / PT;
        partition_kernel<<<pg,   NB,   0, stream>>>(sidx, tidx, enorm, esgn,
                                                    bbase, bcur0, recs, n_edges);
        bucket_accum    <<<K,    1024, 0, stream>>>(input, recs, bbase,
                                                    out, n_nodes);
    } else {
        hipMemsetAsync(d_out, 0, (size_t)out_size * sizeof(float), stream);
        size_t threads_total = (size_t)n_edges * 8;
        int grid = (int)((threads_total + NB - 1) / NB);
        graphconv_scatter<<<grid, NB, 0, stream>>>(input, sidx, tidx, enorm, esgn,
                                                   out, n_edges);
    }
}